// Round 4
// baseline (298.644 us; speedup 1.0000x reference)
//
#include <hip/hip_runtime.h>

#define B_LEN 32
#define C_LEN 512
#define L_LEN 4096
#define H_LEN 8
#define WIN 9
#define PADW 4

// ---------------- Kernel 1: conv partial over a C-split ----------------
// grid (L/1024, B, nsplit), block 256. Thread t owns l = l0 + 4t .. 4t+3.
// Double-buffered async staging: ALL staging (bulk + halos) goes through
// global_load_lds, so there is no VGPR->LDS round-trip and therefore no
// vmcnt(0) wait before the compute FMAs; the only drain is at the barrier,
// ~9k cycles after issue (>> 900 cyc HBM latency). Edge-block halos are
// zeroed with a ds_write of constants (uniform branch, no vmem dep).
// LDS 2*4*1032*4 = 33 KB -> 4 blocks/CU.
#define K1_LT 1024
#define K1_CC 4
#define K1_ST 1032 // row: [0..4) left halo | [4..1028) bulk | [1028..1032) right halo

__device__ inline void gload_lds16(const float* g, float* l) {
  __builtin_amdgcn_global_load_lds(
      (const __attribute__((address_space(1))) void*)g,
      (__attribute__((address_space(3))) void*)l, 16, 0, 0);
}

__global__ __launch_bounds__(256, 4) void conv_partial(
    const float* __restrict__ x, const float* __restrict__ W,
    float* __restrict__ part, int cper)
{
  __shared__ float xs[2][K1_CC][K1_ST];
  const int t = threadIdx.x;
  const int lane = t & 63;
  const int wid = t >> 6; // wave id = staged row
  const int l0 = blockIdx.x * K1_LT;
  const int b = blockIdx.y;
  const int cbase = blockIdx.z * cper;
  const float* xb = x + (size_t)b * C_LEN * L_LEN;
  const int nchunk = cper / K1_CC;

  float acc[H_LEN][4];
#pragma unroll
  for (int h = 0; h < H_LEN; ++h)
#pragma unroll
    for (int j = 0; j < 4; ++j) acc[h][j] = 0.f;

  // stage: wave `wid` loads channel row (cbase + chunk*4 + wid), fully async
  auto STAGE = [&](int buf, int chunk) {
    const int c = cbase + chunk * K1_CC + wid;
    const float* src = xb + (size_t)c * L_LEN + l0;
    float* dstrow = &xs[buf][wid][0];
#pragma unroll
    for (int q = 0; q < 4; ++q)
      gload_lds16(src + q * 256 + lane * 4, dstrow + 4 + q * 256);
    if (l0 > 0) { // left halo in-bounds: async lds load from lane 0
      if (lane == 0) gload_lds16(src - 4, dstrow);
    } else if (lane == 0) {
      *reinterpret_cast<float4*>(dstrow) = make_float4(0.f, 0.f, 0.f, 0.f);
    }
    if (l0 + K1_LT < L_LEN) { // right halo
      if (lane == 0) gload_lds16(src + K1_LT, dstrow + 4 + K1_LT);
    } else if (lane == 0) {
      *reinterpret_cast<float4*>(dstrow + 4 + K1_LT) = make_float4(0.f, 0.f, 0.f, 0.f);
    }
  };

  STAGE(0, 0);
  __syncthreads(); // vmcnt(0) drain + barrier

  int buf = 0;
  for (int chunk = 0; chunk < nchunk; ++chunk) {
    if (chunk + 1 < nchunk) STAGE(buf ^ 1, chunk + 1); // prefetch, no wait
    const int c0 = cbase + chunk * K1_CC;
#pragma unroll
    for (int c = 0; c < K1_CC; ++c) {
      float xv[12];
      const float4 a0 = *reinterpret_cast<const float4*>(&xs[buf][c][4 * t]);
      const float4 a1 = *reinterpret_cast<const float4*>(&xs[buf][c][4 * t + 4]);
      const float4 a2 = *reinterpret_cast<const float4*>(&xs[buf][c][4 * t + 8]);
      xv[0] = a0.x; xv[1] = a0.y; xv[2]  = a0.z; xv[3]  = a0.w;
      xv[4] = a1.x; xv[5] = a1.y; xv[6]  = a1.z; xv[7]  = a1.w;
      xv[8] = a2.x; xv[9] = a2.y; xv[10] = a2.z; xv[11] = a2.w;
      const float* Wc = W + (size_t)(c0 + c) * WIN; // wave-uniform address
#pragma unroll
      for (int h = 0; h < H_LEN; ++h) {
        const float* Wh = Wc + (size_t)h * (C_LEN * WIN);
#pragma unroll
        for (int w = 0; w < WIN; ++w) {
          const float wv = Wh[w]; // uniform -> SGPR
#pragma unroll
          for (int j = 0; j < 4; ++j)
            acc[h][j] = fmaf(xv[w + j], wv, acc[h][j]);
        }
      }
    }
    __syncthreads(); // drains prefetch vmcnt, then barrier
    buf ^= 1;
  }

  float* dst = part + ((size_t)blockIdx.z * B_LEN * H_LEN + (size_t)b * H_LEN) * L_LEN
             + l0 + 4 * t;
#pragma unroll
  for (int h = 0; h < H_LEN; ++h) {
    float4 v;
    v.x = acc[h][0]; v.y = acc[h][1]; v.z = acc[h][2]; v.w = acc[h][3];
    *reinterpret_cast<float4*>(dst + (size_t)h * L_LEN) = v;
  }
}

// ---------------- Kernel 2: sum partials + softmax over L ----------------
__global__ __launch_bounds__(256) void softmax_rows(
    const float* __restrict__ part, float* __restrict__ focus, int nsplit)
{
  __shared__ float red[256];
  const int r = blockIdx.x; // b*H + h
  const int t = threadIdx.x;
  const size_t PART = (size_t)B_LEN * H_LEN * L_LEN;
  float v[16];
#pragma unroll
  for (int k = 0; k < 4; ++k) {
    const int i4 = (t + 256 * k) * 4;
    float4 a = *reinterpret_cast<const float4*>(&part[(size_t)r * L_LEN + i4]);
    v[4 * k + 0] = a.x; v[4 * k + 1] = a.y; v[4 * k + 2] = a.z; v[4 * k + 3] = a.w;
  }
  for (int s = 1; s < nsplit; ++s) {
#pragma unroll
    for (int k = 0; k < 4; ++k) {
      const int i4 = (t + 256 * k) * 4;
      float4 a = *reinterpret_cast<const float4*>(&part[(size_t)s * PART + (size_t)r * L_LEN + i4]);
      v[4 * k + 0] += a.x; v[4 * k + 1] += a.y; v[4 * k + 2] += a.z; v[4 * k + 3] += a.w;
    }
  }
  // bias b[h] is constant along L -> softmax-invariant -> skipped
  float m = v[0];
#pragma unroll
  for (int k = 1; k < 16; ++k) m = fmaxf(m, v[k]);
  red[t] = m;
  __syncthreads();
  for (int s = 128; s > 0; s >>= 1) {
    if (t < s) red[t] = fmaxf(red[t], red[t + s]);
    __syncthreads();
  }
  m = red[0];
  __syncthreads();
  float sum = 0.f;
#pragma unroll
  for (int k = 0; k < 16; ++k) { v[k] = __expf(v[k] - m); sum += v[k]; }
  red[t] = sum;
  __syncthreads();
  for (int s = 128; s > 0; s >>= 1) {
    if (t < s) red[t] += red[t + s];
    __syncthreads();
  }
  const float inv = 1.f / red[0];
#pragma unroll
  for (int k = 0; k < 4; ++k) {
    const int i4 = (t + 256 * k) * 4;
    float4 a;
    a.x = v[4 * k + 0] * inv; a.y = v[4 * k + 1] * inv;
    a.z = v[4 * k + 2] * inv; a.w = v[4 * k + 3] * inv;
    *reinterpret_cast<float4*>(&focus[(size_t)r * L_LEN + i4]) = a;
  }
}

// ---------------- Kernel 3a: partial pooled over an L-split ----------------
// grid (C/64, B, K3_NS), block 256 -> 1024 blocks (4/CU, 16 waves/CU).
#define K3_ST 68
#define K3_NS 4

__global__ __launch_bounds__(256) void pool_partial(
    const float* __restrict__ x, const float* __restrict__ focus,
    float* __restrict__ pool2)
{
  __shared__ float xs[64 * K3_ST];
  const int t = threadIdx.x;
  const int cl = t & 63;
  const int p = t >> 6;                              // h-group 0..3 (wave-uniform)
  const int pu = __builtin_amdgcn_readfirstlane(p);  // force SGPR for focus addressing
  const int b = blockIdx.y;
  const int c0 = blockIdx.x * 64;
  const int lbeg = blockIdx.z * (L_LEN / K3_NS);
  const float* f0 = focus + ((size_t)b * H_LEN + pu) * L_LEN;
  const float* f1 = f0 + 4 * (size_t)L_LEN;
  const float* xb = x + (size_t)b * C_LEN * L_LEN;
  const int srow = t >> 4;
  const int scol = (t & 15) * 4;
  float acc0 = 0.f, acc1 = 0.f;

  for (int l0 = lbeg; l0 < lbeg + L_LEN / K3_NS; l0 += 64) {
    __syncthreads();
#pragma unroll
    for (int pass = 0; pass < 4; ++pass) {
      const int c = srow + pass * 16;
      float4 v = *reinterpret_cast<const float4*>(&xb[(size_t)(c0 + c) * L_LEN + l0 + scol]);
      *reinterpret_cast<float4*>(&xs[c * K3_ST + scol]) = v;
    }
    __syncthreads();
#pragma unroll
    for (int l4 = 0; l4 < 16; ++l4) {
      const float4 xv = *reinterpret_cast<const float4*>(&xs[cl * K3_ST + 4 * l4]);
      const int li = l0 + 4 * l4;
      acc0 = fmaf(xv.x, f0[li + 0], acc0);
      acc0 = fmaf(xv.y, f0[li + 1], acc0);
      acc0 = fmaf(xv.z, f0[li + 2], acc0);
      acc0 = fmaf(xv.w, f0[li + 3], acc0);
      acc1 = fmaf(xv.x, f1[li + 0], acc1);
      acc1 = fmaf(xv.y, f1[li + 1], acc1);
      acc1 = fmaf(xv.z, f1[li + 2], acc1);
      acc1 = fmaf(xv.w, f1[li + 3], acc1);
    }
  }
  // partial pooled, layout [ls][b][c][h]
  float* dst = pool2 + (((size_t)blockIdx.z * B_LEN + b) * C_LEN + c0 + cl) * H_LEN;
  dst[p] = acc0;
  dst[p + 4] = acc1;
}

// ---------------- Kernel 3b: sum L-splits, max over heads ----------------
__global__ __launch_bounds__(256) void pool_reduce(
    const float* __restrict__ pool2, float* __restrict__ out)
{
  const int i = blockIdx.x * 256 + threadIdx.x; // over B*C
  float s[H_LEN];
#pragma unroll
  for (int h = 0; h < H_LEN; ++h) s[h] = 0.f;
  for (int ls = 0; ls < K3_NS; ++ls) {
    const float* src = pool2 + ((size_t)ls * B_LEN * C_LEN + i) * H_LEN;
    float4 a = *reinterpret_cast<const float4*>(src);
    float4 b4 = *reinterpret_cast<const float4*>(src + 4);
    s[0] += a.x; s[1] += a.y; s[2] += a.z; s[3] += a.w;
    s[4] += b4.x; s[5] += b4.y; s[6] += b4.z; s[7] += b4.w;
  }
  float m = s[0];
#pragma unroll
  for (int h = 1; h < H_LEN; ++h) m = fmaxf(m, s[h]);
  out[i] = m;
}

extern "C" void kernel_launch(void* const* d_in, const int* in_sizes, int n_in,
                              void* d_out, int out_size, void* d_ws, size_t ws_size,
                              hipStream_t stream)
{
  const float* x = (const float*)d_in[0];
  const float* W = (const float*)d_in[1];
  // d_in[2] = bias: constant along L, softmax-invariant -> no effect on output.
  float* out = (float*)d_out;
  float* ws = (float*)d_ws;

  const size_t PART = (size_t)B_LEN * H_LEN * L_LEN;            // 1M floats
  const size_t POOL2N = (size_t)K3_NS * B_LEN * C_LEN * H_LEN;  // 512K floats
  int nsplit = 8;
  if (ws_size < ((8 + 1) * PART + POOL2N) * sizeof(float)) nsplit = 4;
  if (ws_size < ((4 + 1) * PART + POOL2N) * sizeof(float)) nsplit = 2;
  if (ws_size < ((2 + 1) * PART + POOL2N) * sizeof(float)) nsplit = 1;

  float* part = ws;
  float* focus = ws + (size_t)nsplit * PART;
  float* pool2 = focus + PART;
  const int cper = C_LEN / nsplit;

  hipLaunchKernelGGL(conv_partial, dim3(L_LEN / K1_LT, B_LEN, nsplit), dim3(256), 0,
                     stream, x, W, part, cper);
  hipLaunchKernelGGL(softmax_rows, dim3(B_LEN * H_LEN), dim3(256), 0,
                     stream, part, focus, nsplit);
  hipLaunchKernelGGL(pool_partial, dim3(C_LEN / 64, B_LEN, K3_NS), dim3(256), 0,
                     stream, x, focus, pool2);
  hipLaunchKernelGGL(pool_reduce, dim3((B_LEN * C_LEN) / 256), dim3(256), 0,
                     stream, pool2, out);
}

// Round 5
// 212.877 us; speedup vs baseline: 1.4029x; 1.4029x over previous
//
#include <hip/hip_runtime.h>

#define B_LEN 32
#define C_LEN 512
#define L_LEN 4096
#define H_LEN 8
#define WIN 9
#define PADW 4

// ---------------- Kernel 1: conv partial over a C-split ----------------
// grid (L/512, B, nsplit=8) = 2048 blocks -> 8 blocks/CU, 32 waves/CU (full
// occupancy; VGPR<=64 enforced by launch_bounds). Thread t owns l = l0+2t,2t+1.
// Staging: bulk via global_load_lds (2 wave-instrs/row), halos via lane<1
// VGPR float4 + ds_write, halo loads issued FIRST so their counted vmcnt
// wait does not drain the bulk gloads. Double-buffered; with 8 waves/SIMD
// any residual per-wave stall is hidden by TLP.
#define K1_LT 512
#define K1_CC 4
#define K1_ST 520 // row: [0..4) left halo | [4..516) bulk | [516..520) right halo

__device__ inline void gload_lds16(const float* g, float* l) {
  __builtin_amdgcn_global_load_lds(
      (const __attribute__((address_space(1))) void*)g,
      (__attribute__((address_space(3))) void*)l, 16, 0, 0);
}

__global__ __launch_bounds__(256, 8) void conv_partial(
    const float* __restrict__ x, const float* __restrict__ W,
    float* __restrict__ part, int cper)
{
  __shared__ float xs[2][K1_CC][K1_ST];
  const int t = threadIdx.x;
  const int lane = t & 63;
  const int wid = t >> 6; // wave id = staged row
  const int l0 = blockIdx.x * K1_LT;
  const int b = blockIdx.y;
  const int cbase = blockIdx.z * cper;
  const float* xb = x + (size_t)b * C_LEN * L_LEN;
  const int nchunk = cper / K1_CC;

  float acc[H_LEN][2];
#pragma unroll
  for (int h = 0; h < H_LEN; ++h) { acc[h][0] = 0.f; acc[h][1] = 0.f; }

  // stage: wave `wid` loads channel row (cbase + chunk*4 + wid)
  auto STAGE = [&](int buf, int chunk) {
    const int c = cbase + chunk * K1_CC + wid;
    const float* src = xb + (size_t)c * L_LEN + l0;
    float* dstrow = &xs[buf][wid][0];
    // halo loads FIRST (so waiting on them leaves bulk gloads in flight)
    float4 lh = make_float4(0.f, 0.f, 0.f, 0.f);
    float4 rh = make_float4(0.f, 0.f, 0.f, 0.f);
    if (lane == 0) {
      if (l0 > 0) lh = *reinterpret_cast<const float4*>(src - 4);
      if (l0 + K1_LT < L_LEN) rh = *reinterpret_cast<const float4*>(src + K1_LT);
    }
    gload_lds16(src + lane * 4, dstrow + 4);
    gload_lds16(src + 256 + lane * 4, dstrow + 4 + 256);
    if (lane == 0) {
      *reinterpret_cast<float4*>(dstrow) = lh;
      *reinterpret_cast<float4*>(dstrow + 4 + K1_LT) = rh;
    }
  };

  STAGE(0, 0);
  __syncthreads();

  int buf = 0;
  for (int chunk = 0; chunk < nchunk; ++chunk) {
    if (chunk + 1 < nchunk) STAGE(buf ^ 1, chunk + 1); // prefetch, no wait
    const int c0 = cbase + chunk * K1_CC;
#pragma unroll
    for (int c = 0; c < K1_CC; ++c) {
      // thread needs row idx 2t .. 2t+9 (out l = l0+2t, l0+2t+1)
      const float2* rp = reinterpret_cast<const float2*>(&xs[buf][c][2 * t]);
      float xv[10];
#pragma unroll
      for (int q = 0; q < 5; ++q) {
        const float2 v = rp[q];
        xv[2 * q] = v.x; xv[2 * q + 1] = v.y;
      }
      const float* Wc = W + (size_t)(c0 + c) * WIN; // wave-uniform address
#pragma unroll
      for (int h = 0; h < H_LEN; ++h) {
        const float* Wh = Wc + (size_t)h * (C_LEN * WIN);
#pragma unroll
        for (int w = 0; w < WIN; ++w) {
          const float wv = Wh[w]; // uniform -> SGPR
          acc[h][0] = fmaf(xv[w], wv, acc[h][0]);
          acc[h][1] = fmaf(xv[w + 1], wv, acc[h][1]);
        }
      }
    }
    __syncthreads(); // drains prefetch vmcnt/lgkm, then barrier
    buf ^= 1;
  }

  float* dst = part + ((size_t)blockIdx.z * B_LEN * H_LEN + (size_t)b * H_LEN) * L_LEN
             + l0 + 2 * t;
#pragma unroll
  for (int h = 0; h < H_LEN; ++h) {
    float2 v;
    v.x = acc[h][0]; v.y = acc[h][1];
    *reinterpret_cast<float2*>(dst + (size_t)h * L_LEN) = v;
  }
}

// ---------------- Kernel 2: sum partials + softmax over L ----------------
__global__ __launch_bounds__(256) void softmax_rows(
    const float* __restrict__ part, float* __restrict__ focus, int nsplit)
{
  __shared__ float red[256];
  const int r = blockIdx.x; // b*H + h
  const int t = threadIdx.x;
  const size_t PART = (size_t)B_LEN * H_LEN * L_LEN;
  float v[16];
#pragma unroll
  for (int k = 0; k < 4; ++k) {
    const int i4 = (t + 256 * k) * 4;
    float4 a = *reinterpret_cast<const float4*>(&part[(size_t)r * L_LEN + i4]);
    v[4 * k + 0] = a.x; v[4 * k + 1] = a.y; v[4 * k + 2] = a.z; v[4 * k + 3] = a.w;
  }
  for (int s = 1; s < nsplit; ++s) {
#pragma unroll
    for (int k = 0; k < 4; ++k) {
      const int i4 = (t + 256 * k) * 4;
      float4 a = *reinterpret_cast<const float4*>(&part[(size_t)s * PART + (size_t)r * L_LEN + i4]);
      v[4 * k + 0] += a.x; v[4 * k + 1] += a.y; v[4 * k + 2] += a.z; v[4 * k + 3] += a.w;
    }
  }
  // bias b[h] is constant along L -> softmax-invariant -> skipped
  float m = v[0];
#pragma unroll
  for (int k = 1; k < 16; ++k) m = fmaxf(m, v[k]);
  red[t] = m;
  __syncthreads();
  for (int s = 128; s > 0; s >>= 1) {
    if (t < s) red[t] = fmaxf(red[t], red[t + s]);
    __syncthreads();
  }
  m = red[0];
  __syncthreads();
  float sum = 0.f;
#pragma unroll
  for (int k = 0; k < 16; ++k) { v[k] = __expf(v[k] - m); sum += v[k]; }
  red[t] = sum;
  __syncthreads();
  for (int s = 128; s > 0; s >>= 1) {
    if (t < s) red[t] += red[t + s];
    __syncthreads();
  }
  const float inv = 1.f / red[0];
#pragma unroll
  for (int k = 0; k < 4; ++k) {
    const int i4 = (t + 256 * k) * 4;
    float4 a;
    a.x = v[4 * k + 0] * inv; a.y = v[4 * k + 1] * inv;
    a.z = v[4 * k + 2] * inv; a.w = v[4 * k + 3] * inv;
    *reinterpret_cast<float4*>(&focus[(size_t)r * L_LEN + i4]) = a;
  }
}

// ---------------- Kernel 3a: partial pooled over an L-split ----------------
// grid (C/64, B, K3_NS), block 256 -> 1024 blocks (4/CU, 16 waves/CU).
#define K3_ST 68
#define K3_NS 4

__global__ __launch_bounds__(256) void pool_partial(
    const float* __restrict__ x, const float* __restrict__ focus,
    float* __restrict__ pool2)
{
  __shared__ float xs[64 * K3_ST];
  const int t = threadIdx.x;
  const int cl = t & 63;
  const int p = t >> 6;                              // h-group 0..3 (wave-uniform)
  const int pu = __builtin_amdgcn_readfirstlane(p);  // force SGPR for focus addressing
  const int b = blockIdx.y;
  const int c0 = blockIdx.x * 64;
  const int lbeg = blockIdx.z * (L_LEN / K3_NS);
  const float* f0 = focus + ((size_t)b * H_LEN + pu) * L_LEN;
  const float* f1 = f0 + 4 * (size_t)L_LEN;
  const float* xb = x + (size_t)b * C_LEN * L_LEN;
  const int srow = t >> 4;
  const int scol = (t & 15) * 4;
  float acc0 = 0.f, acc1 = 0.f;

  for (int l0 = lbeg; l0 < lbeg + L_LEN / K3_NS; l0 += 64) {
    __syncthreads();
#pragma unroll
    for (int pass = 0; pass < 4; ++pass) {
      const int c = srow + pass * 16;
      float4 v = *reinterpret_cast<const float4*>(&xb[(size_t)(c0 + c) * L_LEN + l0 + scol]);
      *reinterpret_cast<float4*>(&xs[c * K3_ST + scol]) = v;
    }
    __syncthreads();
#pragma unroll
    for (int l4 = 0; l4 < 16; ++l4) {
      const float4 xv = *reinterpret_cast<const float4*>(&xs[cl * K3_ST + 4 * l4]);
      const int li = l0 + 4 * l4;
      acc0 = fmaf(xv.x, f0[li + 0], acc0);
      acc0 = fmaf(xv.y, f0[li + 1], acc0);
      acc0 = fmaf(xv.z, f0[li + 2], acc0);
      acc0 = fmaf(xv.w, f0[li + 3], acc0);
      acc1 = fmaf(xv.x, f1[li + 0], acc1);
      acc1 = fmaf(xv.y, f1[li + 1], acc1);
      acc1 = fmaf(xv.z, f1[li + 2], acc1);
      acc1 = fmaf(xv.w, f1[li + 3], acc1);
    }
  }
  // partial pooled, layout [ls][b][c][h]
  float* dst = pool2 + (((size_t)blockIdx.z * B_LEN + b) * C_LEN + c0 + cl) * H_LEN;
  dst[p] = acc0;
  dst[p + 4] = acc1;
}

// ---------------- Kernel 3b: sum L-splits, max over heads ----------------
__global__ __launch_bounds__(256) void pool_reduce(
    const float* __restrict__ pool2, float* __restrict__ out)
{
  const int i = blockIdx.x * 256 + threadIdx.x; // over B*C
  float s[H_LEN];
#pragma unroll
  for (int h = 0; h < H_LEN; ++h) s[h] = 0.f;
  for (int ls = 0; ls < K3_NS; ++ls) {
    const float* src = pool2 + ((size_t)ls * B_LEN * C_LEN + i) * H_LEN;
    float4 a = *reinterpret_cast<const float4*>(src);
    float4 b4 = *reinterpret_cast<const float4*>(src + 4);
    s[0] += a.x; s[1] += a.y; s[2] += a.z; s[3] += a.w;
    s[4] += b4.x; s[5] += b4.y; s[6] += b4.z; s[7] += b4.w;
  }
  float m = s[0];
#pragma unroll
  for (int h = 1; h < H_LEN; ++h) m = fmaxf(m, s[h]);
  out[i] = m;
}

extern "C" void kernel_launch(void* const* d_in, const int* in_sizes, int n_in,
                              void* d_out, int out_size, void* d_ws, size_t ws_size,
                              hipStream_t stream)
{
  const float* x = (const float*)d_in[0];
  const float* W = (const float*)d_in[1];
  // d_in[2] = bias: constant along L, softmax-invariant -> no effect on output.
  float* out = (float*)d_out;
  float* ws = (float*)d_ws;

  const size_t PART = (size_t)B_LEN * H_LEN * L_LEN;            // 1M floats
  const size_t POOL2N = (size_t)K3_NS * B_LEN * C_LEN * H_LEN;  // 512K floats
  int nsplit = 8;
  if (ws_size < ((8 + 1) * PART + POOL2N) * sizeof(float)) nsplit = 4;
  if (ws_size < ((4 + 1) * PART + POOL2N) * sizeof(float)) nsplit = 2;
  if (ws_size < ((2 + 1) * PART + POOL2N) * sizeof(float)) nsplit = 1;

  float* part = ws;
  float* focus = ws + (size_t)nsplit * PART;
  float* pool2 = focus + PART;
  const int cper = C_LEN / nsplit;

  hipLaunchKernelGGL(conv_partial, dim3(L_LEN / K1_LT, B_LEN, nsplit), dim3(256), 0,
                     stream, x, W, part, cper);
  hipLaunchKernelGGL(softmax_rows, dim3(B_LEN * H_LEN), dim3(256), 0,
                     stream, part, focus, nsplit);
  hipLaunchKernelGGL(pool_partial, dim3(C_LEN / 64, B_LEN, K3_NS), dim3(256), 0,
                     stream, x, focus, pool2);
  hipLaunchKernelGGL(pool_reduce, dim3((B_LEN * C_LEN) / 256), dim3(256), 0,
                     stream, pool2, out);
}